// Round 3
// baseline (1680.317 us; speedup 1.0000x reference)
//
#include <hip/hip_runtime.h>
#include <math.h>

#define T_   32
#define C_   128
#define GD_  64
#define NH_  4
#define HD_  32
#define C4_  512
#define HW_  1024

#define POOL_BYTES 75264

// Dynamic LDS pool layout (fp32 everywhere):
//   0      : xs  [32x128]  (x)          ; Phases F/G: hmid chunk [32x256] spans 0..32K
//   16384  : Q   [32x128]
//   32768  : K   [32x128] -> o1 [32x128]
//   49152  : V   [32x128] -> KV [4x32x32] -> x2 [32x128]
//   65536  : gs  [32x64]
//   73728  : ksum[128]
//   74240  : stats[128]  (mu1[32], rstd1[32], mu2[32], rstd2[32])
//   74752  : zden[128]
__global__ __launch_bounds__(256, 2) void fused_linattn_f32(
    const float* __restrict__ x,  const float* __restrict__ gui,
    const float* __restrict__ Wq, const float* __restrict__ bq,
    const float* __restrict__ Wk, const float* __restrict__ bk,
    const float* __restrict__ Wv, const float* __restrict__ bv,
    const float* __restrict__ g1, const float* __restrict__ be1,
    const float* __restrict__ g2, const float* __restrict__ be2,
    const float* __restrict__ W1, const float* __restrict__ b1,
    const float* __restrict__ W2, const float* __restrict__ b2,
    float* __restrict__ out)
{
    extern __shared__ __align__(16) char pool[];
    float* xs    = (float*)(pool);
    float* Qs    = (float*)(pool + 16384);
    float* Ks    = (float*)(pool + 32768);
    float* Vs    = (float*)(pool + 49152);
    float* gsm   = (float*)(pool + 65536);
    float* ksum  = (float*)(pool + 73728);
    float* stats = (float*)(pool + 74240);
    float* zden  = (float*)(pool + 74752);
    float* hmid  = (float*)(pool);          // 32x256 fp32 chunk, phases F/G
    float* o1    = Ks;                      // overlays K after phase C
    float* KV    = Vs;                      // overlays V after phase C
    float* x2    = Vs;                      // overlays KV after phase D

    const int n   = blockIdx.x;
    const int b   = n >> 10;
    const int hw  = n & 1023;
    const int tid = threadIdx.x;

    const float* xb = x + (size_t)b * (T_*C_*HW_) + hw;

    // ---- Phase A: stage x (strided) and guidance (contiguous) ----
    #pragma unroll
    for (int i = 0; i < 16; ++i) {
        int idx = tid + i*256;                      // idx = t*C_ + c
        xs[idx] = xb[(size_t)idx * HW_];
    }
    const float* gb = gui + b * (T_*GD_);
    #pragma unroll
    for (int i = 0; i < 8; ++i) {
        int idx = tid + i*256;
        gsm[idx] = gb[idx];
    }
    __syncthreads();

    // ---- Phase B: Q,K,V projections, 4t x 4c register tile per thread ----
    {
        const int cg = tid & 31, tg = tid >> 5;
        const int c0 = cg * 4, t0 = tg * 4;
        float aq[4][4], ak[4][4], av[4][4];
        {
            float4 vb_q = *reinterpret_cast<const float4*>(bq + c0);
            float4 vb_k = *reinterpret_cast<const float4*>(bk + c0);
            float4 vb_v = *reinterpret_cast<const float4*>(bv + c0);
            #pragma unroll
            for (int t = 0; t < 4; ++t) {
                aq[t][0]=vb_q.x; aq[t][1]=vb_q.y; aq[t][2]=vb_q.z; aq[t][3]=vb_q.w;
                ak[t][0]=vb_k.x; ak[t][1]=vb_k.y; ak[t][2]=vb_k.z; ak[t][3]=vb_k.w;
                av[t][0]=vb_v.x; av[t][1]=vb_v.y; av[t][2]=vb_v.z; av[t][3]=vb_v.w;
            }
        }
        #pragma unroll 2
        for (int j = 0; j < C_; ++j) {
            float xv[4];
            #pragma unroll
            for (int t = 0; t < 4; ++t) xv[t] = xs[(t0+t)*C_ + j];
            float4 wq = *reinterpret_cast<const float4*>(Wq + j*C_ + c0);
            float4 wk = *reinterpret_cast<const float4*>(Wk + j*C_ + c0);
            float4 wv = *reinterpret_cast<const float4*>(Wv + j*C_ + c0);
            #pragma unroll
            for (int t = 0; t < 4; ++t) {
                aq[t][0] = fmaf(xv[t], wq.x, aq[t][0]);
                aq[t][1] = fmaf(xv[t], wq.y, aq[t][1]);
                aq[t][2] = fmaf(xv[t], wq.z, aq[t][2]);
                aq[t][3] = fmaf(xv[t], wq.w, aq[t][3]);
                ak[t][0] = fmaf(xv[t], wk.x, ak[t][0]);
                ak[t][1] = fmaf(xv[t], wk.y, ak[t][1]);
                ak[t][2] = fmaf(xv[t], wk.z, ak[t][2]);
                ak[t][3] = fmaf(xv[t], wk.w, ak[t][3]);
                av[t][0] = fmaf(xv[t], wv.x, av[t][0]);
                av[t][1] = fmaf(xv[t], wv.y, av[t][1]);
                av[t][2] = fmaf(xv[t], wv.z, av[t][2]);
                av[t][3] = fmaf(xv[t], wv.w, av[t][3]);
            }
        }
        #pragma unroll 2
        for (int j = 0; j < GD_; ++j) {
            float gv[4];
            #pragma unroll
            for (int t = 0; t < 4; ++t) gv[t] = gsm[(t0+t)*GD_ + j];
            float4 wq = *reinterpret_cast<const float4*>(Wq + (C_+j)*C_ + c0);
            float4 wk = *reinterpret_cast<const float4*>(Wk + (C_+j)*C_ + c0);
            #pragma unroll
            for (int t = 0; t < 4; ++t) {
                aq[t][0] = fmaf(gv[t], wq.x, aq[t][0]);
                aq[t][1] = fmaf(gv[t], wq.y, aq[t][1]);
                aq[t][2] = fmaf(gv[t], wq.z, aq[t][2]);
                aq[t][3] = fmaf(gv[t], wq.w, aq[t][3]);
                ak[t][0] = fmaf(gv[t], wk.x, ak[t][0]);
                ak[t][1] = fmaf(gv[t], wk.y, ak[t][1]);
                ak[t][2] = fmaf(gv[t], wk.z, ak[t][2]);
                ak[t][3] = fmaf(gv[t], wk.w, ak[t][3]);
            }
        }
        #pragma unroll
        for (int t = 0; t < 4; ++t) {
            #pragma unroll
            for (int cc = 0; cc < 4; ++cc) {
                int off = (t0+t)*C_ + c0 + cc;
                float q = aq[t][cc];
                Qs[off] = (q > 0.f) ? (q + 1.f) : __expf(q);   // elu(q)+1
                float k = ak[t][cc];
                Ks[off] = (k > 0.f) ? (k + 1.f) : __expf(k);   // elu(k)+1
                Vs[off] = av[t][cc];
            }
        }
    }
    __syncthreads();

    // ---- Phase C: KV in registers; ksum; ln1 stats ----
    // (1/T on V and *T at the end cancel exactly; omitted)
    float kvreg[16];
    #pragma unroll 1
    for (int i = 0; i < 16; ++i) {
        int idx = tid + i*256;                       // idx = h*1024 + d*32 + v
        int h = idx >> 10, d = (idx >> 5) & 31, vd = idx & 31;
        const float* kc = Ks + h*HD_ + d;
        const float* vc = Vs + h*HD_ + vd;
        float s = 0.f;
        #pragma unroll
        for (int t = 0; t < T_; ++t) s = fmaf(kc[t*C_], vc[t*C_], s);
        kvreg[i] = s;
    }
    if (tid < 128) {
        float s = 0.f;
        #pragma unroll
        for (int t = 0; t < T_; ++t) s += Ks[t*C_ + tid];
        ksum[tid] = s;
    } else if (tid < 160) {
        int t = tid - 128;
        float m = 0.f;
        for (int c = 0; c < C_; ++c) m += xs[t*C_ + c];
        m *= (1.f/C_);
        float v = 0.f;
        for (int c = 0; c < C_; ++c) { float dd = xs[t*C_ + c] - m; v = fmaf(dd, dd, v); }
        stats[t]      = m;
        stats[32 + t] = rsqrtf(v * (1.f/C_) + 1e-5f);
    }
    __syncthreads();
    // write KV over V (all V reads done); zden from ksum+Q
    #pragma unroll
    for (int i = 0; i < 16; ++i) KV[tid + i*256] = kvreg[i];
    if (tid < 128) {
        int l = tid >> 2, h = tid & 3;
        const float* qr = Qs + l*C_ + h*HD_;
        const float* kb = ksum + h*HD_;
        float s = 0.f;
        #pragma unroll
        for (int d = 0; d < HD_; ++d) s = fmaf(qr[d], kb[d], s);
        zden[l*NH_ + h] = 1.f / (s + 1e-6f);
    }
    __syncthreads();

    // ---- Phase D: attn + ln1 residual -> o1 (over K) ----
    #pragma unroll 1
    for (int i = 0; i < 16; ++i) {
        int idx = tid + i*256;
        int l = idx >> 7, c = idx & 127;
        int h = c >> 5, vd = c & 31;
        const float* qr  = Qs + l*C_ + h*HD_;
        const float* kvc = KV + h*(HD_*HD_) + vd;
        float s = 0.f;
        #pragma unroll
        for (int d = 0; d < HD_; ++d) s = fmaf(qr[d], kvc[d*HD_], s);
        float attn = s * zden[l*NH_ + h];
        float lnx = (xs[idx] - stats[l]) * stats[32+l] * g1[c] + be1[c];
        o1[idx] = attn + lnx;
    }
    __syncthreads();

    // ---- Phase E: ln2 stats, x2 = ln2(o1) (over KV) ----
    if (tid < 32) {
        int t = tid;
        float m = 0.f;
        for (int c = 0; c < C_; ++c) m += o1[t*C_ + c];
        m *= (1.f/C_);
        float v = 0.f;
        for (int c = 0; c < C_; ++c) { float dd = o1[t*C_ + c] - m; v = fmaf(dd, dd, v); }
        stats[64 + t] = m;
        stats[96 + t] = rsqrtf(v * (1.f/C_) + 1e-5f);
    }
    __syncthreads();
    #pragma unroll 1
    for (int i = 0; i < 16; ++i) {
        int idx = tid + i*256;
        int t = idx >> 7, c = idx & 127;
        x2[idx] = (o1[idx] - stats[64+t]) * stats[96+t] * g2[c] + be2[c];
    }
    __syncthreads();

    // ---- Phases F/G: MLP in two 256-col chunks; hmid chunk overlays xs+Q ----
    const int cg = tid & 31, tg = tid >> 5;
    const int c0g = cg * 4, t0g = tg * 4;
    float accg[4][4];
    #pragma unroll
    for (int t = 0; t < 4; ++t)
        #pragma unroll
        for (int cc = 0; cc < 4; ++cc) accg[t][cc] = 0.f;

    #pragma unroll 1
    for (int mh = 0; mh < 2; ++mh) {
        // F-chunk: hmid[32][256] = gelu(x2 @ W1[:, mh*256 : mh*256+256] + b1)
        {
            const int m0 = cg * 8;                  // 32 groups x 8 cols = 256
            float acc[4][8];
            #pragma unroll
            for (int t = 0; t < 4; ++t)
                #pragma unroll
                for (int mm = 0; mm < 8; ++mm) acc[t][mm] = 0.f;
            #pragma unroll 2
            for (int j = 0; j < C_; ++j) {
                float xv[4];
                #pragma unroll
                for (int t = 0; t < 4; ++t) xv[t] = x2[(t0g+t)*C_ + j];
                const float* wr = W1 + j*C4_ + mh*256 + m0;
                float4 w0 = *reinterpret_cast<const float4*>(wr);
                float4 w1 = *reinterpret_cast<const float4*>(wr + 4);
                #pragma unroll
                for (int t = 0; t < 4; ++t) {
                    acc[t][0] = fmaf(xv[t], w0.x, acc[t][0]);
                    acc[t][1] = fmaf(xv[t], w0.y, acc[t][1]);
                    acc[t][2] = fmaf(xv[t], w0.z, acc[t][2]);
                    acc[t][3] = fmaf(xv[t], w0.w, acc[t][3]);
                    acc[t][4] = fmaf(xv[t], w1.x, acc[t][4]);
                    acc[t][5] = fmaf(xv[t], w1.y, acc[t][5]);
                    acc[t][6] = fmaf(xv[t], w1.z, acc[t][6]);
                    acc[t][7] = fmaf(xv[t], w1.w, acc[t][7]);
                }
            }
            #pragma unroll
            for (int t = 0; t < 4; ++t) {
                #pragma unroll
                for (int mm = 0; mm < 8; ++mm) {
                    float v = acc[t][mm] + b1[mh*256 + m0 + mm];
                    float ge = 0.5f * v * (1.f + erff(v * 0.70710678118654752f));
                    hmid[(t0g+t)*256 + m0 + mm] = ge;
                }
            }
        }
        __syncthreads();
        // G-partial: accg += hmid @ W2[mh*256 : mh*256+256, :]
        #pragma unroll 2
        for (int j = 0; j < 256; ++j) {
            float hv[4];
            #pragma unroll
            for (int t = 0; t < 4; ++t) hv[t] = hmid[(t0g+t)*256 + j];
            float4 w = *reinterpret_cast<const float4*>(W2 + (mh*256 + j)*C_ + c0g);
            #pragma unroll
            for (int t = 0; t < 4; ++t) {
                accg[t][0] = fmaf(hv[t], w.x, accg[t][0]);
                accg[t][1] = fmaf(hv[t], w.y, accg[t][1]);
                accg[t][2] = fmaf(hv[t], w.z, accg[t][2]);
                accg[t][3] = fmaf(hv[t], w.w, accg[t][3]);
            }
        }
        __syncthreads();   // protect hmid before next F-chunk overwrite
    }

    // ---- epilogue: y = o1 + accg + b2, strided store ----
    {
        float* ob = out + (size_t)b * (T_*C_*HW_) + hw;
        float4 vb2 = *reinterpret_cast<const float4*>(b2 + c0g);
        float bb[4] = {vb2.x, vb2.y, vb2.z, vb2.w};
        #pragma unroll
        for (int t = 0; t < 4; ++t) {
            #pragma unroll
            for (int cc = 0; cc < 4; ++cc) {
                int tt = t0g + t, c = c0g + cc;
                float y = o1[tt*C_ + c] + accg[t][cc] + bb[cc];
                ob[(size_t)(tt*C_ + c) * HW_] = y;
            }
        }
    }
}

extern "C" void kernel_launch(void* const* d_in, const int* in_sizes, int n_in,
                              void* d_out, int out_size, void* d_ws, size_t ws_size,
                              hipStream_t stream)
{
    const float* x   = (const float*)d_in[0];
    const float* gui = (const float*)d_in[1];
    const float* Wq  = (const float*)d_in[2];
    const float* bq  = (const float*)d_in[3];
    const float* Wk  = (const float*)d_in[4];
    const float* bk  = (const float*)d_in[5];
    const float* Wv  = (const float*)d_in[6];
    const float* bv  = (const float*)d_in[7];
    const float* g1  = (const float*)d_in[8];
    const float* be1 = (const float*)d_in[9];
    const float* g2  = (const float*)d_in[10];
    const float* be2 = (const float*)d_in[11];
    const float* W1  = (const float*)d_in[12];
    const float* b1  = (const float*)d_in[13];
    const float* W2  = (const float*)d_in[14];
    const float* b2  = (const float*)d_in[15];

    (void)hipFuncSetAttribute((const void*)fused_linattn_f32,
                              hipFuncAttributeMaxDynamicSharedMemorySize,
                              POOL_BYTES);

    fused_linattn_f32<<<dim3(4096), dim3(256), POOL_BYTES, stream>>>(
        x, gui, Wq, bq, Wk, bk, Wv, bv, g1, be1, g2, be2, W1, b1, W2, b2,
        (float*)d_out);
}

// Round 4
// 738.404 us; speedup vs baseline: 2.2756x; 2.2756x over previous
//
#include <hip/hip_runtime.h>
#include <hip/hip_bf16.h>
#include <math.h>

#define T_   32
#define C_   128
#define GD_  64
#define KQK_ 192
#define NH_  4
#define HD_  32
#define C4_  512
#define HW_  1024

typedef unsigned short u16;
typedef __attribute__((ext_vector_type(8))) short short8;
typedef __attribute__((ext_vector_type(4))) float f32x4;

// ---- ws layout (u16 element offsets): W^T[n][k] bf16 planes (hi, lo) ----
#define WQH 0
#define WQL 24576
#define WKH 49152
#define WKL 73728
#define WVH 98304
#define WVL 114688
#define W1H 131072
#define W1L 196608
#define W2H 262144
#define W2L 327680

// ---- LDS pool byte offsets ----
#define AXH   0        // [32][200] u16 (x|g hi), rows padded to 200 u16 (=400B, 16B-mult)
#define AXL   12800    // [32][200] u16 (lo)
#define HMH   0        // [32][136] u16 gelu hi (overlays AXH in MLP phase)
#define HML   8704     // [32][136] u16 gelu lo
#define QS    25600    // [32][129] f32
#define KS    42112    // [32][129] f32 -> o1
#define R3    58624    // Vs [32][129] f32 -> KV [4][32][33] f32 -> x2 planes
#define X2H   58624    // [32][136] u16
#define X2L   67328    // [32][136] u16
#define KSUM  76032    // 128 f32
#define STATS 76544    // 128 f32: mu1[32] rstd1[32] mu2[32] rstd2[32]
#define ZDEN  77056    // 128 f32
#define POOLB 77568

__device__ __forceinline__ float b2f(u16 u) {
    unsigned int x = ((unsigned int)u) << 16;
    float f; __builtin_memcpy(&f, &x, 4); return f;
}
__device__ __forceinline__ u16 f2b(float f) {
    __hip_bfloat16 h = __float2bfloat16(f);
    u16 u; __builtin_memcpy(&u, &h, 2); return u;
}

// ---- prep: split weights to bf16 hi/lo, transposed to [n][K] ----
__global__ void prep_weights(const float* __restrict__ Wq, const float* __restrict__ Wk,
                             const float* __restrict__ Wv, const float* __restrict__ W1,
                             const float* __restrict__ W2, u16* __restrict__ wsp)
{
    int e = blockIdx.x * 256 + threadIdx.x;
    const float* src; int e2, k, n, K; int oh, ol;
    if (e < 24576)       { src = Wq; e2 = e;          k = e2 >> 7; n = e2 & 127; K = KQK_; oh = WQH; ol = WQL; }
    else if (e < 49152)  { src = Wk; e2 = e - 24576;  k = e2 >> 7; n = e2 & 127; K = KQK_; oh = WKH; ol = WKL; }
    else if (e < 65536)  { src = Wv; e2 = e - 49152;  k = e2 >> 7; n = e2 & 127; K = C_;   oh = WVH; ol = WVL; }
    else if (e < 131072) { src = W1; e2 = e - 65536;  k = e2 >> 9; n = e2 & 511; K = C_;   oh = W1H; ol = W1L; }
    else                 { src = W2; e2 = e - 131072; k = e2 >> 7; n = e2 & 127; K = C4_;  oh = W2H; ol = W2L; }
    float w = src[e2];                       // src row-major [K][N], e2 = k*N + n
    u16 hb = f2b(w);
    float rem = w - b2f(hb);
    wsp[oh + n * K + k] = hb;
    wsp[ol + n * K + k] = f2b(rem);
}

__global__ __launch_bounds__(256, 2) void fused_linattn_mfma(
    const float* __restrict__ x,  const float* __restrict__ gui,
    const float* __restrict__ bq, const float* __restrict__ bk, const float* __restrict__ bv,
    const float* __restrict__ g1, const float* __restrict__ be1,
    const float* __restrict__ g2, const float* __restrict__ be2,
    const float* __restrict__ b1, const float* __restrict__ b2,
    const u16* __restrict__ wsp,
    float* __restrict__ out)
{
    extern __shared__ __align__(16) char pool[];
    float* ksum  = (float*)(pool + KSUM);
    float* stats = (float*)(pool + STATS);
    float* zden  = (float*)(pool + ZDEN);

    const int bi  = blockIdx.x;
    const int n_  = ((bi & 7) << 9) | (bi >> 3);   // XCD swizzle: adjacent hw -> same XCD
    const int b   = n_ >> 10;
    const int hw  = n_ & 1023;
    const int tid = threadIdx.x;
    const int lane = tid & 63, wv = tid >> 6;
    const int l16  = lane & 15, quad = lane >> 4;

    // ---- Phase A: stage x (strided) + guidance, split to bf16 hi/lo A-planes ----
    {
        const float* xb = x + (size_t)b * (T_*C_*HW_) + hw;
        #pragma unroll
        for (int i = 0; i < 16; ++i) {
            int idx = tid + i*256;                 // t*128 + c
            float v = xb[(size_t)idx * HW_];
            int t = idx >> 7, c = idx & 127;
            u16 hb = f2b(v);
            *(u16*)(pool + AXH + t*400 + c*2) = hb;
            *(u16*)(pool + AXL + t*400 + c*2) = f2b(v - b2f(hb));
        }
        const float* gb = gui + b * (T_*GD_);
        #pragma unroll
        for (int i = 0; i < 8; ++i) {
            int idx = tid + i*256;                 // t*64 + j
            float v = gb[idx];
            int t = idx >> 6, j = idx & 63;
            u16 hb = f2b(v);
            *(u16*)(pool + AXH + t*400 + (128 + j)*2) = hb;
            *(u16*)(pool + AXL + t*400 + (128 + j)*2) = f2b(v - b2f(hb));
        }
    }
    __syncthreads();

    // ---- Phase B: QKV projections via split-bf16 MFMA ----
    // A-frag: A[m=l16][k=quad*8+j]; B-frag: W^T[n=l16][k=quad*8+j]; C: col=l16,row=quad*4+r
    {
        // ---- Q ----
        f32x4 acc[2][2];
        #pragma unroll
        for (int mt = 0; mt < 2; ++mt)
            #pragma unroll
            for (int nt = 0; nt < 2; ++nt) acc[mt][nt] = (f32x4){0.f,0.f,0.f,0.f};
        #pragma unroll
        for (int ks = 0; ks < 6; ++ks) {
            short8 ah[2], al[2];
            #pragma unroll
            for (int mt = 0; mt < 2; ++mt) {
                ah[mt] = *(const short8*)(pool + AXH + (mt*16 + l16)*400 + ks*64 + quad*16);
                al[mt] = *(const short8*)(pool + AXL + (mt*16 + l16)*400 + ks*64 + quad*16);
            }
            #pragma unroll
            for (int nt = 0; nt < 2; ++nt) {
                int n = (wv*2 + nt)*16 + l16;
                short8 bh = *(const short8*)(wsp + WQH + n*KQK_ + ks*32 + quad*8);
                short8 bl = *(const short8*)(wsp + WQL + n*KQK_ + ks*32 + quad*8);
                #pragma unroll
                for (int mt = 0; mt < 2; ++mt) {
                    acc[mt][nt] = __builtin_amdgcn_mfma_f32_16x16x32_bf16(ah[mt], bh, acc[mt][nt], 0, 0, 0);
                    acc[mt][nt] = __builtin_amdgcn_mfma_f32_16x16x32_bf16(ah[mt], bl, acc[mt][nt], 0, 0, 0);
                    acc[mt][nt] = __builtin_amdgcn_mfma_f32_16x16x32_bf16(al[mt], bh, acc[mt][nt], 0, 0, 0);
                }
            }
        }
        #pragma unroll
        for (int nt = 0; nt < 2; ++nt) {
            int col = (wv*2 + nt)*16 + l16;
            float bias = bq[col];
            #pragma unroll
            for (int mt = 0; mt < 2; ++mt)
                #pragma unroll
                for (int r = 0; r < 4; ++r) {
                    int row = mt*16 + quad*4 + r;
                    float q = acc[mt][nt][r] + bias;
                    *(float*)(pool + QS + (row*129 + col)*4) = (q > 0.f) ? q + 1.f : __expf(q);
                }
        }
        // ---- K ----
        #pragma unroll
        for (int mt = 0; mt < 2; ++mt)
            #pragma unroll
            for (int nt = 0; nt < 2; ++nt) acc[mt][nt] = (f32x4){0.f,0.f,0.f,0.f};
        #pragma unroll
        for (int ks = 0; ks < 6; ++ks) {
            short8 ah[2], al[2];
            #pragma unroll
            for (int mt = 0; mt < 2; ++mt) {
                ah[mt] = *(const short8*)(pool + AXH + (mt*16 + l16)*400 + ks*64 + quad*16);
                al[mt] = *(const short8*)(pool + AXL + (mt*16 + l16)*400 + ks*64 + quad*16);
            }
            #pragma unroll
            for (int nt = 0; nt < 2; ++nt) {
                int n = (wv*2 + nt)*16 + l16;
                short8 bh = *(const short8*)(wsp + WKH + n*KQK_ + ks*32 + quad*8);
                short8 bl = *(const short8*)(wsp + WKL + n*KQK_ + ks*32 + quad*8);
                #pragma unroll
                for (int mt = 0; mt < 2; ++mt) {
                    acc[mt][nt] = __builtin_amdgcn_mfma_f32_16x16x32_bf16(ah[mt], bh, acc[mt][nt], 0, 0, 0);
                    acc[mt][nt] = __builtin_amdgcn_mfma_f32_16x16x32_bf16(ah[mt], bl, acc[mt][nt], 0, 0, 0);
                    acc[mt][nt] = __builtin_amdgcn_mfma_f32_16x16x32_bf16(al[mt], bh, acc[mt][nt], 0, 0, 0);
                }
            }
        }
        #pragma unroll
        for (int nt = 0; nt < 2; ++nt) {
            int col = (wv*2 + nt)*16 + l16;
            float bias = bk[col];
            #pragma unroll
            for (int mt = 0; mt < 2; ++mt)
                #pragma unroll
                for (int r = 0; r < 4; ++r) {
                    int row = mt*16 + quad*4 + r;
                    float k = acc[mt][nt][r] + bias;
                    *(float*)(pool + KS + (row*129 + col)*4) = (k > 0.f) ? k + 1.f : __expf(k);
                }
        }
        // ---- V ----
        #pragma unroll
        for (int mt = 0; mt < 2; ++mt)
            #pragma unroll
            for (int nt = 0; nt < 2; ++nt) acc[mt][nt] = (f32x4){0.f,0.f,0.f,0.f};
        #pragma unroll
        for (int ks = 0; ks < 4; ++ks) {
            short8 ah[2], al[2];
            #pragma unroll
            for (int mt = 0; mt < 2; ++mt) {
                ah[mt] = *(const short8*)(pool + AXH + (mt*16 + l16)*400 + ks*64 + quad*16);
                al[mt] = *(const short8*)(pool + AXL + (mt*16 + l16)*400 + ks*64 + quad*16);
            }
            #pragma unroll
            for (int nt = 0; nt < 2; ++nt) {
                int n = (wv*2 + nt)*16 + l16;
                short8 bh = *(const short8*)(wsp + WVH + n*C_ + ks*32 + quad*8);
                short8 bl = *(const short8*)(wsp + WVL + n*C_ + ks*32 + quad*8);
                #pragma unroll
                for (int mt = 0; mt < 2; ++mt) {
                    acc[mt][nt] = __builtin_amdgcn_mfma_f32_16x16x32_bf16(ah[mt], bh, acc[mt][nt], 0, 0, 0);
                    acc[mt][nt] = __builtin_amdgcn_mfma_f32_16x16x32_bf16(ah[mt], bl, acc[mt][nt], 0, 0, 0);
                    acc[mt][nt] = __builtin_amdgcn_mfma_f32_16x16x32_bf16(al[mt], bh, acc[mt][nt], 0, 0, 0);
                }
            }
        }
        #pragma unroll
        for (int nt = 0; nt < 2; ++nt) {
            int col = (wv*2 + nt)*16 + l16;
            float bias = bv[col];
            #pragma unroll
            for (int mt = 0; mt < 2; ++mt)
                #pragma unroll
                for (int r = 0; r < 4; ++r) {
                    int row = mt*16 + quad*4 + r;
                    *(float*)(pool + R3 + (row*129 + col)*4) = acc[mt][nt][r] + bias;
                }
        }
    }
    __syncthreads();

    // ---- Phase C1: KV (regs), ksum, ln1 stats ----
    float kvreg[16];
    {
        const float* Ksp = (const float*)(pool + KS);
        const float* Vsp = (const float*)(pool + R3);
        #pragma unroll 1
        for (int i = 0; i < 16; ++i) {
            int idx = tid + i*256;                   // h*1024 + d*32 + v
            int h = idx >> 10, d = (idx >> 5) & 31, v = idx & 31;
            const float* kc = Ksp + h*HD_ + d;
            const float* vc = Vsp + h*HD_ + v;
            float s = 0.f;
            #pragma unroll
            for (int t = 0; t < T_; ++t) s = fmaf(kc[t*129], vc[t*129], s);
            kvreg[i] = s;
        }
        if (tid < 128) {
            float s = 0.f;
            #pragma unroll
            for (int t = 0; t < T_; ++t) s += Ksp[t*129 + tid];
            ksum[tid] = s;
        } else if (tid < 160) {
            int t = tid - 128;
            float m = 0.f;
            for (int c = 0; c < C_; ++c)
                m += b2f(*(const u16*)(pool + AXH + t*400 + c*2)) + b2f(*(const u16*)(pool + AXL + t*400 + c*2));
            m *= (1.f/C_);
            float v = 0.f;
            for (int c = 0; c < C_; ++c) {
                float xv = b2f(*(const u16*)(pool + AXH + t*400 + c*2)) + b2f(*(const u16*)(pool + AXL + t*400 + c*2));
                float dd = xv - m; v = fmaf(dd, dd, v);
            }
            stats[t]      = m;
            stats[32 + t] = rsqrtf(v * (1.f/C_) + 1e-5f);
        }
    }
    __syncthreads();

    // ---- Phase C2: KV -> LDS (padded 33), zden ----
    {
        float* KVp = (float*)(pool + R3);
        #pragma unroll
        for (int i = 0; i < 16; ++i) {
            int idx = tid + i*256;
            int h = idx >> 10, d = (idx >> 5) & 31, v = idx & 31;
            KVp[h*1056 + d*33 + v] = kvreg[i];
        }
        if (tid < 128) {
            int l = tid >> 2, h = tid & 3;
            const float* qr = (const float*)(pool + QS) + l*129 + h*HD_;
            const float* kb = ksum + h*HD_;
            float s = 0.f;
            #pragma unroll
            for (int d = 0; d < HD_; ++d) s = fmaf(qr[d], kb[d], s);
            zden[l*NH_ + h] = 1.f / (s + 1e-6f);
        }
    }
    __syncthreads();

    // ---- Phase D: attn + ln1(x) -> o1 (overlays Ks) ----
    {
        const float* KVp = (const float*)(pool + R3);
        const float* Qsp = (const float*)(pool + QS);
        float* o1 = (float*)(pool + KS);
        #pragma unroll 1
        for (int i = 0; i < 16; ++i) {
            int idx = tid + i*256;
            int l = idx >> 7, c = idx & 127;
            int h = c >> 5, v = c & 31;
            const float* qr  = Qsp + l*129 + h*HD_;
            const float* kvc = KVp + h*1056 + v;
            float s = 0.f;
            #pragma unroll
            for (int d = 0; d < HD_; ++d) s = fmaf(qr[d], kvc[d*33], s);
            float attn = s * zden[l*NH_ + h];
            float xv = b2f(*(const u16*)(pool + AXH + l*400 + c*2)) + b2f(*(const u16*)(pool + AXL + l*400 + c*2));
            float lnx = (xv - stats[l]) * stats[32+l] * g1[c] + be1[c];
            o1[l*129 + c] = attn + lnx;
        }
    }
    __syncthreads();

    // ---- Phase E1: ln2 stats ----
    if (tid < 32) {
        const float* o1 = (const float*)(pool + KS);
        int t = tid;
        float m = 0.f;
        for (int c = 0; c < C_; ++c) m += o1[t*129 + c];
        m *= (1.f/C_);
        float v = 0.f;
        for (int c = 0; c < C_; ++c) { float dd = o1[t*129 + c] - m; v = fmaf(dd, dd, v); }
        stats[64 + t] = m;
        stats[96 + t] = rsqrtf(v * (1.f/C_) + 1e-5f);
    }
    __syncthreads();

    // ---- Phase E2: x2 = ln2(o1), split to bf16 planes (overlays KV) ----
    {
        const float* o1 = (const float*)(pool + KS);
        #pragma unroll 1
        for (int i = 0; i < 16; ++i) {
            int idx = tid + i*256;
            int t = idx >> 7, c = idx & 127;
            float v = (o1[t*129 + c] - stats[64+t]) * stats[96+t] * g2[c] + be2[c];
            u16 hb = f2b(v);
            *(u16*)(pool + X2H + t*272 + c*2) = hb;
            *(u16*)(pool + X2L + t*272 + c*2) = f2b(v - b2f(hb));
        }
    }
    __syncthreads();

    // ---- Phases F/G: MLP in 4 chunks of 128 cols; MLP2 accumulates in regs ----
    f32x4 accO[2][2];
    #pragma unroll
    for (int mt = 0; mt < 2; ++mt)
        #pragma unroll
        for (int nt = 0; nt < 2; ++nt) accO[mt][nt] = (f32x4){0.f,0.f,0.f,0.f};

    #pragma unroll 1
    for (int mh = 0; mh < 4; ++mh) {
        // F: hmid = gelu(x2 @ W1[:, chunk] + b1)
        {
            f32x4 accH[2][2];
            #pragma unroll
            for (int mt = 0; mt < 2; ++mt)
                #pragma unroll
                for (int nt = 0; nt < 2; ++nt) accH[mt][nt] = (f32x4){0.f,0.f,0.f,0.f};
            #pragma unroll
            for (int ks = 0; ks < 4; ++ks) {
                short8 ah[2], al[2];
                #pragma unroll
                for (int mt = 0; mt < 2; ++mt) {
                    ah[mt] = *(const short8*)(pool + X2H + (mt*16 + l16)*272 + ks*64 + quad*16);
                    al[mt] = *(const short8*)(pool + X2L + (mt*16 + l16)*272 + ks*64 + quad*16);
                }
                #pragma unroll
                for (int nt = 0; nt < 2; ++nt) {
                    int gn = mh*128 + (wv*2 + nt)*16 + l16;
                    short8 bh = *(const short8*)(wsp + W1H + gn*C_ + ks*32 + quad*8);
                    short8 bl = *(const short8*)(wsp + W1L + gn*C_ + ks*32 + quad*8);
                    #pragma unroll
                    for (int mt = 0; mt < 2; ++mt) {
                        accH[mt][nt] = __builtin_amdgcn_mfma_f32_16x16x32_bf16(ah[mt], bh, accH[mt][nt], 0, 0, 0);
                        accH[mt][nt] = __builtin_amdgcn_mfma_f32_16x16x32_bf16(ah[mt], bl, accH[mt][nt], 0, 0, 0);
                        accH[mt][nt] = __builtin_amdgcn_mfma_f32_16x16x32_bf16(al[mt], bh, accH[mt][nt], 0, 0, 0);
                    }
                }
            }
            #pragma unroll
            for (int nt = 0; nt < 2; ++nt) {
                int gcol = mh*128 + (wv*2 + nt)*16 + l16;
                int colc = (wv*2 + nt)*16 + l16;
                float bias = b1[gcol];
                #pragma unroll
                for (int mt = 0; mt < 2; ++mt)
                    #pragma unroll
                    for (int r = 0; r < 4; ++r) {
                        int row = mt*16 + quad*4 + r;
                        float v = accH[mt][nt][r] + bias;
                        float ge = 0.5f * v * (1.f + erff(v * 0.70710678118654752f));
                        u16 hb = f2b(ge);
                        *(u16*)(pool + HMH + row*272 + colc*2) = hb;
                        *(u16*)(pool + HML + row*272 + colc*2) = f2b(ge - b2f(hb));
                    }
            }
        }
        __syncthreads();
        // G: accO += hmid @ W2[chunk, :]
        {
            #pragma unroll
            for (int ks = 0; ks < 4; ++ks) {
                short8 ah[2], al[2];
                #pragma unroll
                for (int mt = 0; mt < 2; ++mt) {
                    ah[mt] = *(const short8*)(pool + HMH + (mt*16 + l16)*272 + ks*64 + quad*16);
                    al[mt] = *(const short8*)(pool + HML + (mt*16 + l16)*272 + ks*64 + quad*16);
                }
                #pragma unroll
                for (int nt = 0; nt < 2; ++nt) {
                    int n = (wv*2 + nt)*16 + l16;
                    short8 bh = *(const short8*)(wsp + W2H + n*C4_ + mh*128 + ks*32 + quad*8);
                    short8 bl = *(const short8*)(wsp + W2L + n*C4_ + mh*128 + ks*32 + quad*8);
                    #pragma unroll
                    for (int mt = 0; mt < 2; ++mt) {
                        accO[mt][nt] = __builtin_amdgcn_mfma_f32_16x16x32_bf16(ah[mt], bh, accO[mt][nt], 0, 0, 0);
                        accO[mt][nt] = __builtin_amdgcn_mfma_f32_16x16x32_bf16(ah[mt], bl, accO[mt][nt], 0, 0, 0);
                        accO[mt][nt] = __builtin_amdgcn_mfma_f32_16x16x32_bf16(al[mt], bh, accO[mt][nt], 0, 0, 0);
                    }
                }
            }
        }
        __syncthreads();
    }

    // ---- Epilogue: y = o1 + mlp + b2, strided store ----
    {
        const float* o1 = (const float*)(pool + KS);
        float* ob = out + (size_t)b * (T_*C_*HW_) + hw;
        #pragma unroll
        for (int nt = 0; nt < 2; ++nt) {
            int col = (wv*2 + nt)*16 + l16;
            float bias = b2[col];
            #pragma unroll
            for (int mt = 0; mt < 2; ++mt)
                #pragma unroll
                for (int r = 0; r < 4; ++r) {
                    int row = mt*16 + quad*4 + r;
                    float y = o1[row*129 + col] + accO[mt][nt][r] + bias;
                    ob[(size_t)(row*C_ + col) * HW_] = y;
                }
        }
    }
}

extern "C" void kernel_launch(void* const* d_in, const int* in_sizes, int n_in,
                              void* d_out, int out_size, void* d_ws, size_t ws_size,
                              hipStream_t stream)
{
    const float* x   = (const float*)d_in[0];
    const float* gui = (const float*)d_in[1];
    const float* Wq  = (const float*)d_in[2];
    const float* bq  = (const float*)d_in[3];
    const float* Wk  = (const float*)d_in[4];
    const float* bk  = (const float*)d_in[5];
    const float* Wv  = (const float*)d_in[6];
    const float* bv  = (const float*)d_in[7];
    const float* g1  = (const float*)d_in[8];
    const float* be1 = (const float*)d_in[9];
    const float* g2  = (const float*)d_in[10];
    const float* be2 = (const float*)d_in[11];
    const float* W1  = (const float*)d_in[12];
    const float* b1  = (const float*)d_in[13];
    const float* W2  = (const float*)d_in[14];
    const float* b2  = (const float*)d_in[15];
    u16* wsp = (u16*)d_ws;

    prep_weights<<<dim3(768), dim3(256), 0, stream>>>(Wq, Wk, Wv, W1, W2, wsp);

    (void)hipFuncSetAttribute((const void*)fused_linattn_mfma,
                              hipFuncAttributeMaxDynamicSharedMemorySize,
                              POOLB);
    fused_linattn_mfma<<<dim3(4096), dim3(256), POOLB, stream>>>(
        x, gui, bq, bk, bv, g1, be1, g2, be2, b1, b2, wsp, (float*)d_out);
}

// Round 5
// 635.186 us; speedup vs baseline: 2.6454x; 1.1625x over previous
//
#include <hip/hip_runtime.h>
#include <hip/hip_bf16.h>
#include <math.h>

#define T_   32
#define C_   128
#define GD_  64
#define KQK_ 192
#define NH_  4
#define HD_  32
#define C4_  512
#define HW_  1024

typedef unsigned short u16;
typedef __attribute__((ext_vector_type(8))) short short8;
typedef __attribute__((ext_vector_type(4))) float f32x4;

// ---- ws layout (u16 element offsets) ----
#define WQH 0
#define WQL 24576
#define WKH 49152
#define WKL 73728
#define WVH 98304
#define WVL 114688
#define W1H 131072
#define W1L 196608
#define W2H 262144
#define W2L 327680
#define GSH 393216
#define GSL 401408
#define XT  409600           // per-n interleaved: [n][hi 4096 u16 | lo 4096 u16]
#define WS_NEED_BYTES (819200ull + 4096ull*8192ull*2ull)   // 67,928,064

// ---- LDS pool byte offsets ----
#define AX_H  0        // [32][200] u16 (x|g hi), stride 400 B
#define AX_L  12800    // [32][200] u16 (lo)
#define O1B   0        // [32][129] f32 overlays AX after barrier
#define Q_H   25600    // [32][136] u16, stride 272
#define Q_L   34304
#define HM_H  25600    // hmid planes overlay Q in MLP phase
#define HM_L  34304
#define KT_H  43008    // [128][32] u16, stride 64 -> KV^T overlays
#define KT_L  51200
#define X2_H  43008    // [32][136] overlays KV^T after O
#define X2_L  51712
#define VT_H  59392    // [128][32] u16
#define VT_L  67584
#define KSUM  75776    // 128 f32
#define STATS 76288    // 128 f32: mu1[32] rstd1[32] mu2[32] rstd2[32]
#define ZDEN  76800    // 128 f32
#define POOLB 77312

__device__ __forceinline__ float b2f(u16 u) {
    unsigned int x = ((unsigned int)u) << 16;
    float f; __builtin_memcpy(&f, &x, 4); return f;
}
__device__ __forceinline__ u16 f2b(float f) {
    __hip_bfloat16 h = __float2bfloat16(f);
    u16 u; __builtin_memcpy(&u, &h, 2); return u;
}

#define MFMA3(acc, ah, al, bh, bl)                                          \
    acc = __builtin_amdgcn_mfma_f32_16x16x32_bf16(ah, bh, acc, 0, 0, 0);    \
    acc = __builtin_amdgcn_mfma_f32_16x16x32_bf16(ah, bl, acc, 0, 0, 0);    \
    acc = __builtin_amdgcn_mfma_f32_16x16x32_bf16(al, bh, acc, 0, 0, 0);

// ---- prep: split weights (transposed [n][K]) + guidance to bf16 hi/lo ----
__global__ void prep_weights(const float* __restrict__ Wq, const float* __restrict__ Wk,
                             const float* __restrict__ Wv, const float* __restrict__ W1,
                             const float* __restrict__ W2, const float* __restrict__ gui,
                             u16* __restrict__ wsp)
{
    int e = blockIdx.x * 256 + threadIdx.x;
    if (e >= 196608) {                       // guidance tail: 8192 elems
        int idx = e - 196608;
        float v = gui[idx];
        u16 hb = f2b(v);
        wsp[GSH + idx] = hb;
        wsp[GSL + idx] = f2b(v - b2f(hb));
        return;
    }
    const float* src; int e2, k, n, K; int oh, ol;
    if (e < 24576)       { src = Wq; e2 = e;          k = e2 >> 7; n = e2 & 127; K = KQK_; oh = WQH; ol = WQL; }
    else if (e < 49152)  { src = Wk; e2 = e - 24576;  k = e2 >> 7; n = e2 & 127; K = KQK_; oh = WKH; ol = WKL; }
    else if (e < 65536)  { src = Wv; e2 = e - 49152;  k = e2 >> 7; n = e2 & 127; K = C_;   oh = WVH; ol = WVL; }
    else if (e < 131072) { src = W1; e2 = e - 65536;  k = e2 >> 9; n = e2 & 511; K = C_;   oh = W1H; ol = W1L; }
    else                 { src = W2; e2 = e - 131072; k = e2 >> 7; n = e2 & 127; K = C4_;  oh = W2H; ol = W2L; }
    float w = src[e2];
    u16 hb = f2b(w);
    wsp[oh + n * K + k] = hb;
    wsp[ol + n * K + k] = f2b(w - b2f(hb));
}

// ---- transpose x (B,T,C,H,W) -> xT[n][t][c] split bf16 planes (coalesced both sides) ----
__global__ __launch_bounds__(256) void transpose_x(const float* __restrict__ x, u16* __restrict__ wsp)
{
    __shared__ float tile[32][65];
    int bid = blockIdx.x;
    int hq = bid & 15, cq = (bid >> 4) & 3, t = (bid >> 6) & 31, b = bid >> 11;
    int c0 = cq * 32, hw0 = hq * 64;
    int tid = threadIdx.x;
    {
        int i = tid >> 3, j8 = (tid & 7) * 8;
        const float* src = x + ((size_t)((b*32 + t)*128 + c0 + i))*1024 + hw0 + j8;
        float4 v0 = *reinterpret_cast<const float4*>(src);
        float4 v1 = *reinterpret_cast<const float4*>(src + 4);
        tile[i][j8+0]=v0.x; tile[i][j8+1]=v0.y; tile[i][j8+2]=v0.z; tile[i][j8+3]=v0.w;
        tile[i][j8+4]=v1.x; tile[i][j8+5]=v1.y; tile[i][j8+6]=v1.z; tile[i][j8+7]=v1.w;
    }
    __syncthreads();
    {
        int jj = tid >> 2, c8 = (tid & 3) * 8;
        int n = b*1024 + hw0 + jj;
        ushort4 h0, h1, l0, l1;
        u16 hh[8], ll[8];
        #pragma unroll
        for (int ii = 0; ii < 8; ++ii) {
            float v = tile[c8 + ii][jj];
            u16 hb = f2b(v);
            hh[ii] = hb; ll[ii] = f2b(v - b2f(hb));
        }
        h0 = make_ushort4(hh[0],hh[1],hh[2],hh[3]); h1 = make_ushort4(hh[4],hh[5],hh[6],hh[7]);
        l0 = make_ushort4(ll[0],ll[1],ll[2],ll[3]); l1 = make_ushort4(ll[4],ll[5],ll[6],ll[7]);
        u16* dh = wsp + XT + (size_t)n*8192 + t*128 + c0 + c8;
        u16* dl = dh + 4096;
        *reinterpret_cast<ushort4*>(dh)     = h0;
        *reinterpret_cast<ushort4*>(dh + 4) = h1;
        *reinterpret_cast<ushort4*>(dl)     = l0;
        *reinterpret_cast<ushort4*>(dl + 4) = l1;
    }
}

__global__ __launch_bounds__(256, 2) void fused_linattn_mfma(
    const float* __restrict__ x,
    const float* __restrict__ bq, const float* __restrict__ bk, const float* __restrict__ bv,
    const float* __restrict__ g1, const float* __restrict__ be1,
    const float* __restrict__ g2, const float* __restrict__ be2,
    const float* __restrict__ b1, const float* __restrict__ b2,
    const u16* __restrict__ wsp, int use_xt,
    float* __restrict__ out)
{
    extern __shared__ __align__(16) char pool[];
    float* ksum  = (float*)(pool + KSUM);
    float* stats = (float*)(pool + STATS);
    float* zden  = (float*)(pool + ZDEN);

    const int bi  = blockIdx.x;
    const int n_  = ((bi & 7) << 9) | (bi >> 3);
    const int b   = n_ >> 10;
    const int hw  = n_ & 1023;
    const int tid = threadIdx.x;
    const int lane = tid & 63, wv = tid >> 6;
    const int l16  = lane & 15, quad = lane >> 4;

    // ---- Phase A: stage x|g split planes into AX ----
    if (use_xt) {
        const u16* xtb = wsp + XT + (size_t)n_ * 8192;
        #pragma unroll
        for (int i = 0; i < 2; ++i) {
            int off = (tid + i*256) * 8;            // element idx (t*128+c), 8 contiguous
            int t = off >> 7, c = off & 127;
            short8 vh = *reinterpret_cast<const short8*>(xtb + off);
            short8 vl = *reinterpret_cast<const short8*>(xtb + 4096 + off);
            *reinterpret_cast<short8*>(pool + AX_H + t*400 + c*2) = vh;
            *reinterpret_cast<short8*>(pool + AX_L + t*400 + c*2) = vl;
        }
    } else {
        const float* xb = x + (size_t)b * (T_*C_*HW_) + hw;
        #pragma unroll
        for (int i = 0; i < 16; ++i) {
            int idx = tid + i*256;
            float v = xb[(size_t)idx * HW_];
            int t = idx >> 7, c = idx & 127;
            u16 hb = f2b(v);
            *(u16*)(pool + AX_H + t*400 + c*2) = hb;
            *(u16*)(pool + AX_L + t*400 + c*2) = f2b(v - b2f(hb));
        }
    }
    {
        const u16* gh = wsp + GSH + b*2048 + tid*8;
        const u16* gl = wsp + GSL + b*2048 + tid*8;
        int off = tid * 8;                          // t*64 + jg
        int t = off >> 6, jg = off & 63;
        short8 vh = *reinterpret_cast<const short8*>(gh);
        short8 vl = *reinterpret_cast<const short8*>(gl);
        *reinterpret_cast<short8*>(pool + AX_H + t*400 + 256 + jg*2) = vh;
        *reinterpret_cast<short8*>(pool + AX_L + t*400 + 256 + jg*2) = vl;
    }
    __syncthreads();

    // ---- Phase B: QKV projections (split-bf16 MFMA) ----
    {
        f32x4 acc[2][2];
        // ---------------- Q ----------------
        #pragma unroll
        for (int mt = 0; mt < 2; ++mt)
            #pragma unroll
            for (int nt = 0; nt < 2; ++nt) acc[mt][nt] = (f32x4){0.f,0.f,0.f,0.f};
        #pragma unroll
        for (int ks = 0; ks < 6; ++ks) {
            short8 ah[2], al[2];
            #pragma unroll
            for (int mt = 0; mt < 2; ++mt) {
                ah[mt] = *(const short8*)(pool + AX_H + (mt*16 + l16)*400 + ks*64 + quad*16);
                al[mt] = *(const short8*)(pool + AX_L + (mt*16 + l16)*400 + ks*64 + quad*16);
            }
            #pragma unroll
            for (int nt = 0; nt < 2; ++nt) {
                int n = (wv*2 + nt)*16 + l16;
                short8 bh = *(const short8*)(wsp + WQH + n*KQK_ + ks*32 + quad*8);
                short8 bl = *(const short8*)(wsp + WQL + n*KQK_ + ks*32 + quad*8);
                #pragma unroll
                for (int mt = 0; mt < 2; ++mt) { MFMA3(acc[mt][nt], ah[mt], al[mt], bh, bl); }
            }
        }
        #pragma unroll
        for (int nt = 0; nt < 2; ++nt) {
            int col = (wv*2 + nt)*16 + l16;
            float bias = bq[col];
            #pragma unroll
            for (int mt = 0; mt < 2; ++mt)
                #pragma unroll
                for (int r = 0; r < 4; ++r) {
                    int row = mt*16 + quad*4 + r;
                    float q = acc[mt][nt][r] + bias;
                    float qp = (q > 0.f) ? q + 1.f : __expf(q);
                    u16 hb = f2b(qp);
                    *(u16*)(pool + Q_H + row*272 + col*2) = hb;
                    *(u16*)(pool + Q_L + row*272 + col*2) = f2b(qp - b2f(hb));
                }
        }
        // ---------------- K (store transposed) ----------------
        #pragma unroll
        for (int mt = 0; mt < 2; ++mt)
            #pragma unroll
            for (int nt = 0; nt < 2; ++nt) acc[mt][nt] = (f32x4){0.f,0.f,0.f,0.f};
        #pragma unroll
        for (int ks = 0; ks < 6; ++ks) {
            short8 ah[2], al[2];
            #pragma unroll
            for (int mt = 0; mt < 2; ++mt) {
                ah[mt] = *(const short8*)(pool + AX_H + (mt*16 + l16)*400 + ks*64 + quad*16);
                al[mt] = *(const short8*)(pool + AX_L + (mt*16 + l16)*400 + ks*64 + quad*16);
            }
            #pragma unroll
            for (int nt = 0; nt < 2; ++nt) {
                int n = (wv*2 + nt)*16 + l16;
                short8 bh = *(const short8*)(wsp + WKH + n*KQK_ + ks*32 + quad*8);
                short8 bl = *(const short8*)(wsp + WKL + n*KQK_ + ks*32 + quad*8);
                #pragma unroll
                for (int mt = 0; mt < 2; ++mt) { MFMA3(acc[mt][nt], ah[mt], al[mt], bh, bl); }
            }
        }
        #pragma unroll
        for (int nt = 0; nt < 2; ++nt) {
            int col = (wv*2 + nt)*16 + l16;        // channel c
            float bias = bk[col];
            #pragma unroll
            for (int mt = 0; mt < 2; ++mt) {
                u16 hh[4], ll[4];
                #pragma unroll
                for (int r = 0; r < 4; ++r) {
                    float k = acc[mt][nt][r] + bias;
                    float kp = (k > 0.f) ? k + 1.f : __expf(k);
                    u16 hb = f2b(kp);
                    hh[r] = hb; ll[r] = f2b(kp - b2f(hb));
                }
                int base = col*32 + mt*16 + quad*4;  // K^T[c][t]
                *reinterpret_cast<ushort4*>(pool + KT_H + base*2) = make_ushort4(hh[0],hh[1],hh[2],hh[3]);
                *reinterpret_cast<ushort4*>(pool + KT_L + base*2) = make_ushort4(ll[0],ll[1],ll[2],ll[3]);
            }
        }
        // ---------------- V (store transposed) ----------------
        #pragma unroll
        for (int mt = 0; mt < 2; ++mt)
            #pragma unroll
            for (int nt = 0; nt < 2; ++nt) acc[mt][nt] = (f32x4){0.f,0.f,0.f,0.f};
        #pragma unroll
        for (int ks = 0; ks < 4; ++ks) {
            short8 ah[2], al[2];
            #pragma unroll
            for (int mt = 0; mt < 2; ++mt) {
                ah[mt] = *(const short8*)(pool + AX_H + (mt*16 + l16)*400 + ks*64 + quad*16);
                al[mt] = *(const short8*)(pool + AX_L + (mt*16 + l16)*400 + ks*64 + quad*16);
            }
            #pragma unroll
            for (int nt = 0; nt < 2; ++nt) {
                int n = (wv*2 + nt)*16 + l16;
                short8 bh = *(const short8*)(wsp + WVH + n*C_ + ks*32 + quad*8);
                short8 bl = *(const short8*)(wsp + WVL + n*C_ + ks*32 + quad*8);
                #pragma unroll
                for (int mt = 0; mt < 2; ++mt) { MFMA3(acc[mt][nt], ah[mt], al[mt], bh, bl); }
            }
        }
        #pragma unroll
        for (int nt = 0; nt < 2; ++nt) {
            int col = (wv*2 + nt)*16 + l16;
            float bias = bv[col];
            #pragma unroll
            for (int mt = 0; mt < 2; ++mt) {
                u16 hh[4], ll[4];
                #pragma unroll
                for (int r = 0; r < 4; ++r) {
                    float v = acc[mt][nt][r] + bias;
                    u16 hb = f2b(v);
                    hh[r] = hb; ll[r] = f2b(v - b2f(hb));
                }
                int base = col*32 + mt*16 + quad*4;  // V^T[c][t]
                *reinterpret_cast<ushort4*>(pool + VT_H + base*2) = make_ushort4(hh[0],hh[1],hh[2],hh[3]);
                *reinterpret_cast<ushort4*>(pool + VT_L + base*2) = make_ushort4(ll[0],ll[1],ll[2],ll[3]);
            }
        }
    }
    __syncthreads();

    // ---- Phase C: KV MFMA (wave = head) + ln1 stats + ksum ----
    f32x4 kvacc[2][2];
    {
        const int h = wv;
        short8 kah[2], kal[2], kbh[2], kbl[2];
        #pragma unroll
        for (int mt = 0; mt < 2; ++mt) {
            int row = h*32 + mt*16 + l16;           // K^T row = channel (head-local d)
            kah[mt] = *(const short8*)(pool + KT_H + row*64 + quad*16);
            kal[mt] = *(const short8*)(pool + KT_L + row*64 + quad*16);
        }
        #pragma unroll
        for (int nt = 0; nt < 2; ++nt) {
            int row = h*32 + nt*16 + l16;           // V^T row (head-local v)
            kbh[nt] = *(const short8*)(pool + VT_H + row*64 + quad*16);
            kbl[nt] = *(const short8*)(pool + VT_L + row*64 + quad*16);
        }
        #pragma unroll
        for (int mt = 0; mt < 2; ++mt)
            #pragma unroll
            for (int nt = 0; nt < 2; ++nt) {
                kvacc[mt][nt] = (f32x4){0.f,0.f,0.f,0.f};
                MFMA3(kvacc[mt][nt], kah[mt], kal[mt], kbh[nt], kbl[nt]);
            }
    }
    {   // ln1 stats: 8 threads per row t
        int t = tid >> 3, j = tid & 7;
        float m = 0.f, s = 0.f;
        #pragma unroll
        for (int i = 0; i < 16; ++i) {
            int c = j*16 + i;
            float v = b2f(*(const u16*)(pool + AX_H + t*400 + c*2))
                    + b2f(*(const u16*)(pool + AX_L + t*400 + c*2));
            m += v; s = fmaf(v, v, s);
        }
        m += __shfl_xor(m, 1); s += __shfl_xor(s, 1);
        m += __shfl_xor(m, 2); s += __shfl_xor(s, 2);
        m += __shfl_xor(m, 4); s += __shfl_xor(s, 4);
        if (j == 0) {
            float mu = m * (1.f/C_);
            stats[t]      = mu;
            stats[32 + t] = rsqrtf(s * (1.f/C_) - mu*mu + 1e-5f);
        }
    }
    if (tid < 128) {                                // ksum[c] = sum_t K'
        int c = tid;
        float s = 0.f;
        #pragma unroll
        for (int t = 0; t < T_; ++t)
            s += b2f(*(const u16*)(pool + KT_H + c*64 + t*2))
               + b2f(*(const u16*)(pool + KT_L + c*64 + t*2));
        ksum[c] = s;
    }
    __syncthreads();

    // ---- Phase C2: KV^T -> LDS (over K^T); zden on upper waves ----
    {
        const int h = wv;
        #pragma unroll
        for (int nt = 0; nt < 2; ++nt) {
            int vrow = h*32 + nt*16 + l16;          // KV^T[v][d]
            #pragma unroll
            for (int mt = 0; mt < 2; ++mt) {
                u16 hh[4], ll[4];
                #pragma unroll
                for (int r = 0; r < 4; ++r) {
                    float v = kvacc[mt][nt][r];
                    u16 hb = f2b(v);
                    hh[r] = hb; ll[r] = f2b(v - b2f(hb));
                }
                int base = vrow*32 + mt*16 + quad*4;
                *reinterpret_cast<ushort4*>(pool + KT_H + base*2) = make_ushort4(hh[0],hh[1],hh[2],hh[3]);
                *reinterpret_cast<ushort4*>(pool + KT_L + base*2) = make_ushort4(ll[0],ll[1],ll[2],ll[3]);
            }
        }
    }
    if (tid >= 128) {
        int i = tid - 128;
        int l = i >> 2, h = i & 3;
        float s = 0.f;
        #pragma unroll
        for (int d = 0; d < HD_; ++d) {
            int c = h*32 + d;
            float qv = b2f(*(const u16*)(pool + Q_H + l*272 + c*2))
                     + b2f(*(const u16*)(pool + Q_L + l*272 + c*2));
            s = fmaf(qv, ksum[c], s);
        }
        zden[l*NH_ + h] = 1.f / (s + 1e-6f);
    }
    __syncthreads();

    // ---- Phase D: O MFMA (wave = head) + ln1 residual -> regs ----
    float o1reg[2][2][4];
    {
        const int h = wv;
        short8 qah[2], qal[2], obh[2], obl[2];
        #pragma unroll
        for (int mt = 0; mt < 2; ++mt) {
            int row = mt*16 + l16;                  // Q row = token l
            qah[mt] = *(const short8*)(pool + Q_H + row*272 + h*64 + quad*16);
            qal[mt] = *(const short8*)(pool + Q_L + row*272 + h*64 + quad*16);
        }
        #pragma unroll
        for (int nt = 0; nt < 2; ++nt) {
            int row = h*32 + nt*16 + l16;           // KV^T row (v)
            obh[nt] = *(const short8*)(pool + KT_H + row*64 + quad*16);
            obl[nt] = *(const short8*)(pool + KT_L + row*64 + quad*16);
        }
        f32x4 oacc[2][2];
        #pragma unroll
        for (int mt = 0; mt < 2; ++mt)
            #pragma unroll
            for (int nt = 0; nt < 2; ++nt) {
                oacc[mt][nt] = (f32x4){0.f,0.f,0.f,0.f};
                MFMA3(oacc[mt][nt], qah[mt], qal[mt], obh[nt], obl[nt]);
            }
        #pragma unroll
        for (int nt = 0; nt < 2; ++nt) {
            int c = h*32 + nt*16 + l16;
            float g1c = g1[c], be1c = be1[c];
            #pragma unroll
            for (int mt = 0; mt < 2; ++mt)
                #pragma unroll
                for (int r = 0; r < 4; ++r) {
                    int l = mt*16 + quad*4 + r;
                    float attn = oacc[mt][nt][r] * zden[l*NH_ + h];
                    float xv = b2f(*(const u16*)(pool + AX_H + l*400 + c*2))
                             + b2f(*(const u16*)(pool + AX_L + l*400 + c*2));
                    float lnx = (xv - stats[l]) * stats[32+l] * g1c + be1c;
                    o1reg[mt][nt][r] = attn + lnx;
                }
        }
    }
    __syncthreads();

    // ---- Phase D2: write o1 f32 over AX ----
    {
        float* O1 = (float*)(pool + O1B);
        const int h = wv;
        #pragma unroll
        for (int nt = 0; nt < 2; ++nt) {
            int c = h*32 + nt*16 + l16;
            #pragma unroll
            for (int mt = 0; mt < 2; ++mt)
                #pragma unroll
                for (int r = 0; r < 4; ++r) {
                    int l = mt*16 + quad*4 + r;
                    O1[l*129 + c] = o1reg[mt][nt][r];
                }
        }
    }
    __syncthreads();

    // ---- Phase E1: ln2 stats (parallel) ----
    {
        const float* O1 = (const float*)(pool + O1B);
        int t = tid >> 3, j = tid & 7;
        float m = 0.f, s = 0.f;
        #pragma unroll
        for (int i = 0; i < 16; ++i) {
            float v = O1[t*129 + j*16 + i];
            m += v; s = fmaf(v, v, s);
        }
        m += __shfl_xor(m, 1); s += __shfl_xor(s, 1);
        m += __shfl_xor(m, 2); s += __shfl_xor(s, 2);
        m += __shfl_xor(m, 4); s += __shfl_xor(s, 4);
        if (j == 0) {
            float mu = m * (1.f/C_);
            stats[64 + t] = mu;
            stats[96 + t] = rsqrtf(s * (1.f/C_) - mu*mu + 1e-5f);
        }
    }
    __syncthreads();

    // ---- Phase E2: x2 = ln2(o1) split planes (over KV^T region) ----
    {
        const float* O1 = (const float*)(pool + O1B);
        #pragma unroll
        for (int i = 0; i < 16; ++i) {
            int idx = tid + i*256;
            int t = idx >> 7, c = idx & 127;
            float v = (O1[t*129 + c] - stats[64+t]) * stats[96+t] * g2[c] + be2[c];
            u16 hb = f2b(v);
            *(u16*)(pool + X2_H + t*272 + c*2) = hb;
            *(u16*)(pool + X2_L + t*272 + c*2) = f2b(v - b2f(hb));
        }
    }
    __syncthreads();

    // ---- Phases F/G: MLP, 4 chunks of 128; hmid over Q planes ----
    f32x4 accO[2][2];
    #pragma unroll
    for (int mt = 0; mt < 2; ++mt)
        #pragma unroll
        for (int nt = 0; nt < 2; ++nt) accO[mt][nt] = (f32x4){0.f,0.f,0.f,0.f};

    #pragma unroll 1
    for (int mh = 0; mh < 4; ++mh) {
        {
            f32x4 accH[2][2];
            #pragma unroll
            for (int mt = 0; mt < 2; ++mt)
                #pragma unroll
                for (int nt = 0; nt < 2; ++nt) accH[mt][nt] = (f32x4){0.f,0.f,0.f,0.f};
            #pragma unroll
            for (int ks = 0; ks < 4; ++ks) {
                short8 ah[2], al[2];
                #pragma unroll
                for (int mt = 0; mt < 2; ++mt) {
                    ah[mt] = *(const short8*)(pool + X2_H + (mt*16 + l16)*272 + ks*64 + quad*16);
                    al[mt] = *(const short8*)(pool + X2_L + (mt*16 + l16)*272 + ks*64 + quad*16);
                }
                #pragma unroll
                for (int nt = 0; nt < 2; ++nt) {
                    int gn = mh*128 + (wv*2 + nt)*16 + l16;
                    short8 bh = *(const short8*)(wsp + W1H + gn*C_ + ks*32 + quad*8);
                    short8 bl = *(const short8*)(wsp + W1L + gn*C_ + ks*32 + quad*8);
                    #pragma unroll
                    for (int mt = 0; mt < 2; ++mt) { MFMA3(accH[mt][nt], ah[mt], al[mt], bh, bl); }
                }
            }
            #pragma unroll
            for (int nt = 0; nt < 2; ++nt) {
                int gcol = mh*128 + (wv*2 + nt)*16 + l16;
                int colc = (wv*2 + nt)*16 + l16;
                float bias = b1[gcol];
                #pragma unroll
                for (int mt = 0; mt < 2; ++mt)
                    #pragma unroll
                    for (int r = 0; r < 4; ++r) {
                        int row = mt*16 + quad*4 + r;
                        float v = accH[mt][nt][r] + bias;
                        float ge = 0.5f * v * (1.f + erff(v * 0.70710678118654752f));
                        u16 hb = f2b(ge);
                        *(u16*)(pool + HM_H + row*272 + colc*2) = hb;
                        *(u16*)(pool + HM_L + row*272 + colc*2) = f2b(ge - b2f(hb));
                    }
            }
        }
        __syncthreads();
        {
            #pragma unroll
            for (int ks = 0; ks < 4; ++ks) {
                short8 ah[2], al[2];
                #pragma unroll
                for (int mt = 0; mt < 2; ++mt) {
                    ah[mt] = *(const short8*)(pool + HM_H + (mt*16 + l16)*272 + ks*64 + quad*16);
                    al[mt] = *(const short8*)(pool + HM_L + (mt*16 + l16)*272 + ks*64 + quad*16);
                }
                #pragma unroll
                for (int nt = 0; nt < 2; ++nt) {
                    int n = (wv*2 + nt)*16 + l16;
                    short8 bh = *(const short8*)(wsp + W2H + n*C4_ + mh*128 + ks*32 + quad*8);
                    short8 bl = *(const short8*)(wsp + W2L + n*C4_ + mh*128 + ks*32 + quad*8);
                    #pragma unroll
                    for (int mt = 0; mt < 2; ++mt) { MFMA3(accO[mt][nt], ah[mt], al[mt], bh, bl); }
                }
            }
        }
        __syncthreads();
    }

    // ---- Epilogue: y = o1 + mlp + b2, strided store ----
    {
        const float* O1 = (const float*)(pool + O1B);
        float* ob = out + (size_t)b * (T_*C_*HW_) + hw;
        #pragma unroll
        for (int nt = 0; nt < 2; ++nt) {
            int col = (wv*2 + nt)*16 + l16;
            float bias = b2[col];
            #pragma unroll
            for (int mt = 0; mt < 2; ++mt)
                #pragma unroll
                for (int r = 0; r < 4; ++r) {
                    int row = mt*16 + quad*4 + r;
                    float y = O1[row*129 + col] + accO[mt][nt][r] + bias;
                    ob[(size_t)(row*C_ + col) * HW_] = y;
                }
        }
    }
}

extern "C" void kernel_launch(void* const* d_in, const int* in_sizes, int n_in,
                              void* d_out, int out_size, void* d_ws, size_t ws_size,
                              hipStream_t stream)
{
    const float* x   = (const float*)d_in[0];
    const float* gui = (const float*)d_in[1];
    const float* Wq  = (const float*)d_in[2];
    const float* bq  = (const float*)d_in[3];
    const float* Wk  = (const float*)d_in[4];
    const float* bk  = (const float*)d_in[5];
    const float* Wv  = (const float*)d_in[6];
    const float* bv  = (const float*)d_in[7];
    const float* g1  = (const float*)d_in[8];
    const float* be1 = (const float*)d_in[9];
    const float* g2  = (const float*)d_in[10];
    const float* be2 = (const float*)d_in[11];
    const float* W1  = (const float*)d_in[12];
    const float* b1  = (const float*)d_in[13];
    const float* W2  = (const float*)d_in[14];
    const float* b2  = (const float*)d_in[15];
    u16* wsp = (u16*)d_ws;

    int use_xt = (ws_size >= WS_NEED_BYTES) ? 1 : 0;

    prep_weights<<<dim3(800), dim3(256), 0, stream>>>(Wq, Wk, Wv, W1, W2, gui, wsp);
    if (use_xt)
        transpose_x<<<dim3(8192), dim3(256), 0, stream>>>(x, wsp);

    (void)hipFuncSetAttribute((const void*)fused_linattn_mfma,
                              hipFuncAttributeMaxDynamicSharedMemorySize,
                              POOLB);
    fused_linattn_mfma<<<dim3(4096), dim3(256), POOLB, stream>>>(
        x, bq, bk, bv, g1, be1, g2, be2, b1, b2, wsp, use_xt, (float*)d_out);
}